// Round 8
// baseline (265.473 us; speedup 1.0000x reference)
//
#include <hip/hip_runtime.h>
#include <hip/hip_bf16.h>

#define T_STEPS 512
#define BATCH 32
#define NST 64
#define DIM 1024
#define MTOT 16384
#define LOG2E 1.44269504f

typedef _Float16 f16x8 __attribute__((ext_vector_type(8)));
typedef _Float16 f16x4 __attribute__((ext_vector_type(4)));
typedef float f32x4 __attribute__((ext_vector_type(4)));

__device__ __forceinline__ void gl_lds16(const void* g, void* l) {
  __builtin_amdgcn_global_load_lds(
      (const __attribute__((address_space(1))) void*)g,
      (__attribute__((address_space(3))) void*)l, 16, 0, 0);
}

// ---------------- Wf: W in MFMA B-fragment order ----------------
// Wf[kt][ni][lane][8] f16: lane (n=lane&15, kg=lane>>4) holds B[k=kt*32+kg*8+j][n]
// with B[k][n] = W_gate[n&63][k]. Gate order in P cols: [k|q|v|ax].
__global__ __launch_bounds__(64) void wfrag(
    const float* __restrict__ Wk, const float* __restrict__ Wv,
    const float* __restrict__ Wq, const float* __restrict__ Wa,
    _Float16* __restrict__ Wf) {
  const int lane = threadIdx.x;
  const int kt = blockIdx.x >> 4, ni = blockIdx.x & 15;
  const int n = ni * 16 + (lane & 15);
  const int g = n >> 6, rw = n & 63;
  const float* W = (g == 0) ? Wk : (g == 1) ? Wq : (g == 2) ? Wv : Wa;
  const float* src = W + (size_t)rw * DIM + kt * 32 + (lane >> 4) * 8;
  float4 a = *(const float4*)src, bq = *(const float4*)(src + 4);
  f16x8 h = {(_Float16)a.x, (_Float16)a.y, (_Float16)a.z, (_Float16)a.w,
             (_Float16)bq.x, (_Float16)bq.y, (_Float16)bq.z, (_Float16)bq.w};
  *(f16x8*)(Wf + ((size_t)blockIdx.x * 64 + lane) * 8) = h;
}

// ---------------- Projection GEMM v5: dense-transaction staging ----------
// 512 blocks x 128 thr (2 waves). Block tile 32m x 256n (x read once), wave
// tile 16m x 256n (acc 16 frags = 64 VGPR). BK=32, 32 kts. Single barrier/kt;
// ALL staging issued right after the barrier -> 1 full iteration old at the
// next drain. A: dense 1KB/instr global loads (8 rows x 128 B), f32->f16 in
// reg, LDS stride 40. B: gl_lds 1KB/instr straight from frag-ordered Wf (L2).
__global__ __launch_bounds__(128) void proj_gemm(
    const float* __restrict__ x, const _Float16* __restrict__ Wf,
    _Float16* __restrict__ P) {
  const int tid = threadIdx.x;
  const int lane = tid & 63, wv = tid >> 6;
  const int fm = lane & 15, fq = lane >> 4;
  const int m0 = blockIdx.x * 32;

  __shared__ __align__(16) _Float16 Ah[2][32 * 40];
  __shared__ __align__(16) _Float16 Bl[2][8192];  // 16 ni x 64 lanes x 8 halves

  f32x4 acc[16];
#pragma unroll
  for (int ni = 0; ni < 16; ++ni) acc[ni] = (f32x4){0.f, 0.f, 0.f, 0.f};

  // A staging: instr j covers rows j*16 + (tid>>3), bytes (tid&7)*16 of a row.
  const int ar = tid >> 3;   // 0..15
  const int ac = tid & 7;    // 16B chunk within 128B row-segment
  const float* gA = x + (size_t)(m0 + ar) * DIM + ac * 4;
  float4 xr[2][2];
#define LDA(buf, kt)                                                   \
  {                                                                    \
    xr[buf][0] = *(const float4*)(gA + (kt) * 32);                     \
    xr[buf][1] = *(const float4*)(gA + (size_t)16 * DIM + (kt) * 32);  \
  }
#define DSWA(buf)                                                              \
  {                                                                            \
    f16x4 h0 = {(_Float16)xr[buf][0].x, (_Float16)xr[buf][0].y,                \
                (_Float16)xr[buf][0].z, (_Float16)xr[buf][0].w};               \
    f16x4 h1 = {(_Float16)xr[buf][1].x, (_Float16)xr[buf][1].y,                \
                (_Float16)xr[buf][1].z, (_Float16)xr[buf][1].w};               \
    *(f16x4*)&Ah[buf][ar * 40 + ac * 4] = h0;                                  \
    *(f16x4*)&Ah[buf][(ar + 16) * 40 + ac * 4] = h1;                           \
  }
  // B staging: wave wv stages ni = wv*8..wv*8+7; dst = uniform base + lane*16B.
#define STAGEB(buf, kt)                                                  \
  {                                                                      \
    _Pragma("unroll") for (int i = 0; i < 8; ++i) {                      \
      const int nn = wv * 8 + i;                                         \
      gl_lds16(Wf + ((size_t)((kt) * 16 + nn) * 64 + lane) * 8,          \
               &Bl[buf][(nn * 64 + lane) * 8]);                          \
    }                                                                    \
  }

  LDA(0, 0);
  STAGEB(0, 0);
  DSWA(0);       // waits xr[0] via auto vmcnt
  LDA(1, 1);

  for (int kt = 0; kt < 32; ++kt) {
    const int cur = kt & 1;
    __syncthreads();  // Bl[cur] gl_lds + Ah[cur] writes complete (1 iter old)
    if (kt + 1 < 32) {
      STAGEB(cur ^ 1, kt + 1);
      DSWA(cur ^ 1);                       // xr loaded last iter
    }
    if (kt + 2 < 32) LDA(cur, kt + 2);     // xr[cur] free (consumed by DSWA)

    f16x8 af = *(const f16x8*)&Ah[cur][(wv * 16 + fm) * 40 + fq * 8];
#pragma unroll
    for (int ni = 0; ni < 16; ++ni) {
      f16x8 bf = *(const f16x8*)&Bl[cur][(ni * 64 + lane) * 8];
      acc[ni] = __builtin_amdgcn_mfma_f32_16x16x32_f16(af, bf, acc[ni], 0, 0, 0);
    }
  }
#undef LDA
#undef DSWA
#undef STAGEB

  // C/D: col = lane&15, row = fq*4 + reg  [m89-verified]
#pragma unroll
  for (int ni = 0; ni < 16; ++ni)
#pragma unroll
    for (int r = 0; r < 4; ++r)
      P[(size_t)(m0 + wv * 16 + fq * 4 + r) * 256 + ni * 16 + fm] =
          (_Float16)acc[ni][r];
}

// ---------------- kdots: pure-input dot precompute ----------------
// KD[m] = {k_m.k_{m+32}, k_m.q_{m+32}, k_m.q_m, 0}  (m+32 == (t+1,b))
__global__ __launch_bounds__(256) void kdots(const _Float16* __restrict__ P,
                                             float* __restrict__ KD) {
  const int tid = threadIdx.x;
  const int p = tid >> 2, sub = tid & 3;
  const int m = blockIdx.x * 64 + p;
  const bool ok = (m + 32 < MTOT);
  const _Float16* r0 = P + (size_t)m * 256 + sub * 16;
  const _Float16* r1 = P + (size_t)(ok ? m + 32 : m) * 256 + sub * 16;
  f16x8 kta = *(const f16x8*)(r0),      ktb = *(const f16x8*)(r0 + 8);
  f16x8 qta = *(const f16x8*)(r0 + 64), qtb = *(const f16x8*)(r0 + 72);
  f16x8 kna = *(const f16x8*)(r1),      knb = *(const f16x8*)(r1 + 8);
  f16x8 qna = *(const f16x8*)(r1 + 64), qnb = *(const f16x8*)(r1 + 72);
  float KK = 0.f, KQn = 0.f, KQ = 0.f;
#pragma unroll
  for (int j = 0; j < 8; ++j) {
    float k1 = (float)kta[j], k2 = (float)ktb[j];
    KK = fmaf(k1, (float)kna[j], fmaf(k2, (float)knb[j], KK));
    KQn = fmaf(k1, (float)qna[j], fmaf(k2, (float)qnb[j], KQn));
    KQ = fmaf(k1, (float)qta[j], fmaf(k2, (float)qtb[j], KQ));
  }
#define RED4(v)                                                                   \
  {                                                                               \
    int t_ = __builtin_amdgcn_update_dpp(0, __float_as_int(v), 0xB1, 0xF, 0xF, true); \
    v += __int_as_float(t_);                                                      \
    t_ = __builtin_amdgcn_update_dpp(0, __float_as_int(v), 0x4E, 0xF, 0xF, true); \
    v += __int_as_float(t_);                                                      \
  }
  RED4(KK); RED4(KQn); RED4(KQ);
#undef RED4
  if (sub == 0) {
    float4 o = {ok ? KK : 0.f, ok ? KQn : 0.f, KQ, 0.f};
    *(float4*)(KD + (size_t)m * 4) = o;
  }
}

// ---------------- Sequential scan v6: lazy dot expansion ----------------
// 128 blocks = (b, 16-row group), 256 thr = 16 rows x 16 lanes; thread owns
// S[b][r][4c..4c+3]. Serial chain carries only SCALARS (rr, al, cc):
//   rr_{t+1} = al_t*(s_{t-1}.k_{t+1}) + cc_t*(k_t.k_{t+1})
//   Uq_{t+1} = al_t*(s_{t-1}.q_{t+1}) + cc_t*(k_t.q_{t+1})
//   h_t      = al_t*Uq_t + cc_t*(k_t.q_t)
// The two s-dots+reduces use s one step behind -> run concurrent with the
// gate; pure-input dots come precomputed from KD. Chain/step ~= 56 cyc.
__device__ __forceinline__ float red16(float x) {
  int v = __builtin_amdgcn_update_dpp(0, __float_as_int(x), 0xB1, 0xF, 0xF, true);
  x += __int_as_float(v);
  v = __builtin_amdgcn_update_dpp(0, __float_as_int(x), 0x4E, 0xF, 0xF, true);
  x += __int_as_float(v);
  v = __builtin_amdgcn_update_dpp(0, __float_as_int(x), 0x124, 0xF, 0xF, true);
  x += __int_as_float(v);
  v = __builtin_amdgcn_update_dpp(0, __float_as_int(x), 0x128, 0xF, 0xF, true);
  x += __int_as_float(v);
  return x;
}

__global__ __launch_bounds__(256) void scan_kernel(
    const _Float16* __restrict__ P, const float* __restrict__ KD,
    const float* __restrict__ S0, const float* __restrict__ d_alpha,
    const float* __restrict__ b_alpha, float* __restrict__ out,
    float* __restrict__ Sout) {
  const int b = blockIdx.x >> 2;
  const int rg = blockIdx.x & 3;
  const int tid = threadIdx.x;
  const int c = tid & 15;
  const int r = rg * 16 + (tid >> 4);
  const int j0 = c * 4;

  __shared__ __align__(16) float lbuf[2 * 2048];  // 2 chunks x 8 steps x 256
  __shared__ __align__(16) float kdb[2][8][4];

  float s[4];
  {
    float4 v = *(const float4*)(S0 + ((size_t)b * NST + r) * NST + j0);
    s[0] = v.x; s[1] = v.y; s[2] = v.z; s[3] = v.w;
  }
  const float da = d_alpha[r];
  const float ba = b_alpha[r];
  const float mda = -da * LOG2E;

  const int sstep = tid >> 6;       // 0..3
  const int scol = (tid & 63) * 4;  // half-index within a 256-half row
  f16x4 rA[2];
  float4 rKD;
#define GLD(ch)                                                                          \
  {                                                                                      \
    rA[0] = *(const f16x4*)(P + ((size_t)(((ch)*8 + sstep) * BATCH + b)) * 256 + scol);  \
    rA[1] = *(const f16x4*)(P + ((size_t)(((ch)*8 + sstep + 4) * BATCH + b)) * 256 + scol); \
    if (tid < 8) rKD = *(const float4*)(KD + ((size_t)((ch)*8 + tid) * BATCH + b) * 4);  \
  }
#define CVWR(slot)                                                         \
  {                                                                        \
    float4 w0 = {(float)rA[0][0], (float)rA[0][1], (float)rA[0][2],        \
                 (float)rA[0][3]};                                         \
    float4 w1 = {(float)rA[1][0], (float)rA[1][1], (float)rA[1][2],        \
                 (float)rA[1][3]};                                         \
    *(float4*)(lbuf + (slot)*2048 + sstep * 256 + scol) = w0;              \
    *(float4*)(lbuf + (slot)*2048 + (sstep + 4) * 256 + scol) = w1;        \
    if (tid < 8) *(float4*)&kdb[slot][tid][0] = rKD;                       \
  }

  GLD(0); CVWR(0);
  GLD(1); CVWR(1);
  __syncthreads();

  float4 kf[2], qf[2];
  float2 va[2];
#define PREF(tn)                                                           \
  {                                                                        \
    const int pp = (tn)&1;                                                 \
    const float* Pn = lbuf + (((tn) >> 3) & 1) * 2048 + ((tn)&7) * 256;    \
    kf[pp] = *(const float4*)(Pn + j0);                                    \
    qf[pp] = *(const float4*)(Pn + 64 + j0);                               \
    va[pp] = (float2){Pn[128 + r], Pn[192 + r]};                           \
  }

  PREF(0);
  PREF(1);
  float rr, Uq;
  {
    float4 k0v = kf[0], q0v = qf[0];
    float pa = fmaf(s[0], k0v.x, s[1] * k0v.y);
    float pb = fmaf(s[2], k0v.z, s[3] * k0v.w);
    rr = red16(pa + pb);
    float ua = fmaf(s[0], q0v.x, s[1] * q0v.y);
    float ub = fmaf(s[2], q0v.z, s[3] * q0v.w);
    Uq = red16(ua + ub);
  }
  float4 kc = kf[0];

  for (int ch = 0; ch < 64; ++ch) {
#pragma unroll
    for (int si = 0; si < 8; ++si) {
      const int t = ch * 8 + si;
      const int p = t & 1, pn = p ^ 1;
      const float vi = va[p].x;
      const float zc = (va[p].y + ba) * (-LOG2E);
      const float4 kn = kf[pn], qn = qf[pn];
      const float4 kd = *(const float4*)&kdb[(t >> 3) & 1][t & 7][0];
      if (t + 2 < T_STEPS) PREF(t + 2);
      if (si == 1 && ch + 2 < 64) GLD(ch + 2);

      // gate (serial scalar chain from rr)
      float ttv = fmaf(rr, mda, zc);
      ttv = fminf(fmaxf(ttv, -45.f), 45.f);
      const float e = exp2f(ttv);
      const float al = __builtin_amdgcn_rcpf(1.f + e);  // sigmoid(z)
      const float cc = (e * vi) * al;                   // (1-al)*v

      // off-chain: dots of s_{t-1} with NEXT step's k,q (+ concurrent reduces)
      float pa = fmaf(s[0], kn.x, s[1] * kn.y);
      float pb = fmaf(s[2], kn.z, s[3] * kn.w);
      float ua = fmaf(s[0], qn.x, s[1] * qn.y);
      float ub = fmaf(s[2], qn.z, s[3] * qn.w);
      const float SK = red16(pa + pb);
      const float SQ = red16(ua + ub);

      const float h = fmaf(al, Uq, cc * kd.z);  // = S_t . q_t (exact reorder)

      s[0] = fmaf(al, s[0], cc * kc.x);
      s[1] = fmaf(al, s[1], cc * kc.y);
      s[2] = fmaf(al, s[2], cc * kc.z);
      s[3] = fmaf(al, s[3], cc * kc.w);

      rr = fmaf(al, SK, cc * kd.x);  // = S_t . k_{t+1}
      Uq = fmaf(al, SQ, cc * kd.y);  // = S_t . q_{t+1}
      kc = kn;

      if (c == 0) {
        const float sg = __builtin_amdgcn_rcpf(1.f + __expf(-h));
        out[((size_t)t * BATCH + b) * NST + r] = h * h * sg;
      }
    }
    if (ch + 2 < 64) {
      __syncthreads();   // reads of slot ch&1 done
      CVWR(ch & 1);      // stage chunk ch+2 (loaded at si==1)
      __syncthreads();   // visible before chunk ch+2 read
    }
  }
#undef PREF
#undef GLD
#undef CVWR

  float4 o = {s[0], s[1], s[2], s[3]};
  *(float4*)(Sout + ((size_t)b * NST + r) * NST + j0) = o;
}

extern "C" void kernel_launch(void* const* d_in, const int* in_sizes, int n_in,
                              void* d_out, int out_size, void* d_ws, size_t ws_size,
                              hipStream_t stream) {
  const float* x  = (const float*)d_in[0];
  const float* S0 = (const float*)d_in[1];
  const float* Wk = (const float*)d_in[2];
  const float* Wv = (const float*)d_in[3];
  const float* Wq = (const float*)d_in[4];
  const float* Wa = (const float*)d_in[5];
  const float* da = (const float*)d_in[6];
  const float* ba = (const float*)d_in[7];

  float* out  = (float*)d_out;                        // [T,B,64]
  float* Sout = out + (size_t)T_STEPS * BATCH * NST;  // [B,64,64]
  _Float16* P = (_Float16*)d_ws;                                        // 8 MB
  _Float16* Wf = (_Float16*)((char*)d_ws + (size_t)8 * 1024 * 1024);    // 512 KB
  float* KD = (float*)((char*)d_ws + (size_t)8 * 1024 * 1024 + 512 * 1024);  // 256 KB

  wfrag<<<512, 64, 0, stream>>>(Wk, Wv, Wq, Wa, Wf);
  proj_gemm<<<512, 128, 0, stream>>>(x, Wf, P);
  kdots<<<MTOT / 64, 256, 0, stream>>>(P, KD);
  scan_kernel<<<4 * BATCH, 256, 0, stream>>>(P, KD, S0, da, ba, out, Sout);
}